// Round 11
// baseline (458.527 us; speedup 1.0000x reference)
//
#include <hip/hip_runtime.h>
#include <hip/hip_bf16.h>
#include <math.h>

#define NMOD 4
#define NB 4
#define NTOKN 1024
#define CDIM 768
#define HDIM 3072
#define RDIM 16
#define MROWS (NMOD*NB*NTOKN)   // 16384 token rows
#define RPM (NB*NTOKN)          // 4096 positions per modality

typedef __bf16 bf16_t;
typedef __bf16 bf16x4 __attribute__((ext_vector_type(4)));
typedef __bf16 bf16x8 __attribute__((ext_vector_type(8)));
typedef float f32x4 __attribute__((ext_vector_type(4)));

// ---------------- delta1[k][h][c] = fc1_w[h][c] * (B@A); k==0 also emits fc1_w in bf16 ----------------
__global__ void delta1_kernel(const float* __restrict__ fc1w, const float* __restrict__ a1,
                              const float* __restrict__ b1, bf16_t* __restrict__ out,
                              bf16_t* __restrict__ w_bf) {
  int idx = blockIdx.x * blockDim.x + threadIdx.x;
  if (idx >= NMOD*HDIM*CDIM) return;
  int c = idx % CDIM;
  int h = (idx / CDIM) % HDIM;
  int k = idx / (CDIM*HDIM);
  const float* brow = b1 + ((size_t)k*HDIM + h)*RDIM;
  const float* acol = a1 + (size_t)k*RDIM*CDIM + c;
  float s = 0.f;
  #pragma unroll
  for (int r = 0; r < RDIM; ++r) s += brow[r] * acol[r*CDIM];
  const float wv = fc1w[h*CDIM + c];
  out[idx] = (bf16_t)(wv * s);
  if (k == 0) w_bf[h*CDIM + c] = (bf16_t)wv;   // fused weight convert
}

__global__ void delta2_kernel(const float* __restrict__ fc2w, const float* __restrict__ a2,
                              const float* __restrict__ b2, bf16_t* __restrict__ out,
                              bf16_t* __restrict__ w_bf) {
  int idx = blockIdx.x * blockDim.x + threadIdx.x;
  if (idx >= NMOD*CDIM*HDIM) return;
  int h = idx % HDIM;
  int c = (idx / HDIM) % CDIM;
  int k = idx / (HDIM*CDIM);
  const float* brow = b2 + ((size_t)k*CDIM + c)*RDIM;
  const float* acol = a2 + (size_t)k*RDIM*HDIM + h;
  float s = 0.f;
  #pragma unroll
  for (int r = 0; r < RDIM; ++r) s += brow[r] * acol[r*HDIM];
  const float wv = fc2w[c*HDIM + h];
  out[idx] = (bf16_t)(wv * s);
  if (k == 0) w_bf[c*HDIM + h] = (bf16_t)wv;   // fused weight convert
}

// ---------------- gating: normw[t][k]; fused x->bf16; 4 tokens/block ----------------
__global__ void gate_kernel(const float* __restrict__ x, const float* __restrict__ gw,
                            const float* __restrict__ gb, const int* __restrict__ mask,
                            float* __restrict__ normw, bf16_t* __restrict__ x_bf) {
  int t = blockIdx.x * 4 + (threadIdx.x >> 6);
  int lane = threadIdx.x & 63;
  int i = t >> 12;
  int b = (t >> 10) & 3;
  const float* xr = x + (size_t)t * CDIM;
  bf16_t* xo = x_bf + (size_t)t * CDIM;
  float acc[NMOD] = {0.f, 0.f, 0.f, 0.f};
  for (int c = lane; c < CDIM; c += 64) {
    float xv = xr[c];
    xo[c] = (bf16_t)xv;
    #pragma unroll
    for (int e = 0; e < NMOD; ++e) acc[e] += xv * gw[(i*NMOD + e)*CDIM + c];
  }
  #pragma unroll
  for (int e = 0; e < NMOD; ++e) {
    float v = acc[e];
    #pragma unroll
    for (int off = 32; off > 0; off >>= 1) v += __shfl_xor(v, off);
    acc[e] = v;
  }
  if (lane == 0) {
    float lg[NMOD], mx = -1e30f;
    #pragma unroll
    for (int e = 0; e < NMOD; ++e) { lg[e] = acc[e] + gb[i*NMOD + e]; mx = fmaxf(mx, lg[e]); }
    float s = 0.f;
    #pragma unroll
    for (int e = 0; e < NMOD; ++e) { lg[e] = expf(lg[e] - mx); s += lg[e]; }
    float inv = 1.f / s;
    float num[NMOD], den = 0.f;
    #pragma unroll
    for (int k = 0; k < NMOD; ++k) {
      float mk = (float)mask[k*NB + b];
      num[k] = lg[k] * inv * mk;
      den += num[k];
    }
    float mi = (float)mask[i*NB + b];
    float scale = mi / (den + 1e-6f);
    #pragma unroll
    for (int k = 0; k < NMOD; ++k) normw[(size_t)t*4 + k] = num[k] * scale;
  }
}

// ---------------- MERGED base+lora MFMA GEMM (shared-A, swizzled) ----------------
// One block computes BOTH outB[128x128] (W0, +bias) and outL[128x128] (WL[mod]) for the
// same A rows: A staged ONCE, 64 MFMA per K-step per block (2x compute per vmcnt-drain,
// half the block-K-step instances of the z=2 split). Masked (mod,b) blocks skip the lora
// half (block-uniform). grid: (4P/128, N/128).
#define BMT 128
#define BNT 128
#define BKT 64

__device__ __forceinline__ void gload_lds16(const bf16_t* g, bf16_t* l) {
  __builtin_amdgcn_global_load_lds((const __attribute__((address_space(1))) void*)g,
                                   (__attribute__((address_space(3))) void*)l, 16, 0, 0);
}
#define MFMA_BF16 __builtin_amdgcn_mfma_f32_16x16x32_bf16

__global__ __launch_bounds__(256, 2)
void gemm_kernel(const bf16_t* __restrict__ A, const bf16_t* __restrict__ W0,
                 const bf16_t* __restrict__ WL, const float* __restrict__ bias,
                 const int* __restrict__ mask,
                 bf16_t* __restrict__ outB, bf16_t* __restrict__ outL,
                 int K, int N, int P, int modStride, int rowOff, int posOff) {
  __shared__ __align__(16) bf16_t As [BMT * BKT];
  __shared__ __align__(16) bf16_t Bs0[BNT * BKT];
  __shared__ __align__(16) bf16_t Bs1[BNT * BKT];

  const int tid  = threadIdx.x;
  const int lane = tid & 63;
  const int wv   = tid >> 6;
  const int wr   = wv >> 1, wc = wv & 1;
  const int row0 = blockIdx.x * BMT;   // chunk-local
  const int col0 = blockIdx.y * BNT;

  const int mod = row0 / P;            // P % 128 == 0
  const int bb  = (posOff + (row0 % P)) >> 10;
  const bool doL = (mask[mod*NB + bb] != 0);   // lora half needed?
  const int gArow0 = mod * modStride + rowOff + (row0 % P);
  const bf16_t* WpL = WL + (size_t)mod * N * K;

  // staging: 4 rounds of 32 rows; source col-slot swizzled, LDS dest linear (tid*16B)
  const int ldr = tid >> 3;                    // 0..31 (row; row&7 == ldr&7)
  const int ssl = ((tid & 7) ^ (ldr & 7)) * 8; // swizzled source col (elems)
  const bf16_t* Ag  = A   + (size_t)(gArow0 + ldr) * K + ssl;
  const bf16_t* W0g = W0  + (size_t)(col0   + ldr) * K + ssl;
  const bf16_t* W1g = WpL + (size_t)(col0   + ldr) * K + ssl;

  // reads: source slot (kk*4+hi) at row r lives at LDS slot (kk*4+hi)^(r&7); r&7 == fr&7
  const int fr  = lane & 15;
  const int hi  = lane >> 4;
  const int sk0 = ((hi)     ^ (fr & 7)) * 8;   // kk=0
  const int sk1 = ((4 + hi) ^ (fr & 7)) * 8;   // kk=1

  f32x4 acc0[4][4], acc1[4][4];
  #pragma unroll
  for (int i = 0; i < 4; ++i)
    #pragma unroll
    for (int j = 0; j < 4; ++j) {
      acc0[i][j] = (f32x4){0.f, 0.f, 0.f, 0.f};
      acc1[i][j] = (f32x4){0.f, 0.f, 0.f, 0.f};
    }

  for (int k0 = 0; k0 < K; k0 += BKT) {
    __syncthreads();  // protect LDS from overwrite while others still read
    #pragma unroll
    for (int j = 0; j < 4; ++j)
      gload_lds16(Ag  + (size_t)(j*32) * K + k0, &As [tid*8 + j*2048]);
    #pragma unroll
    for (int j = 0; j < 4; ++j)
      gload_lds16(W0g + (size_t)(j*32) * K + k0, &Bs0[tid*8 + j*2048]);
    if (doL) {
      #pragma unroll
      for (int j = 0; j < 4; ++j)
        gload_lds16(W1g + (size_t)(j*32) * K + k0, &Bs1[tid*8 + j*2048]);
    }
    __syncthreads();  // drains vmcnt(0) before s_barrier

    #pragma unroll
    for (int kk = 0; kk < 2; ++kk) {
      const int sk = (kk == 0) ? sk0 : sk1;
      bf16x8 af[4], b0[4];
      #pragma unroll
      for (int mi = 0; mi < 4; ++mi)
        af[mi] = *reinterpret_cast<const bf16x8*>(&As[(wr*64 + mi*16 + fr)*BKT + sk]);
      #pragma unroll
      for (int ni = 0; ni < 4; ++ni)
        b0[ni] = *reinterpret_cast<const bf16x8*>(&Bs0[(wc*64 + ni*16 + fr)*BKT + sk]);
      #pragma unroll
      for (int mi = 0; mi < 4; ++mi)
        #pragma unroll
        for (int ni = 0; ni < 4; ++ni)
          acc0[mi][ni] = MFMA_BF16(af[mi], b0[ni], acc0[mi][ni], 0, 0, 0);
      if (doL) {
        bf16x8 b1[4];
        #pragma unroll
        for (int ni = 0; ni < 4; ++ni)
          b1[ni] = *reinterpret_cast<const bf16x8*>(&Bs1[(wc*64 + ni*16 + fr)*BKT + sk]);
        #pragma unroll
        for (int mi = 0; mi < 4; ++mi)
          #pragma unroll
          for (int ni = 0; ni < 4; ++ni)
            acc1[mi][ni] = MFMA_BF16(af[mi], b1[ni], acc1[mi][ni], 0, 0, 0);
      }
    }
  }

  #pragma unroll
  for (int mi = 0; mi < 4; ++mi) {
    #pragma unroll
    for (int ni = 0; ni < 4; ++ni) {
      const int colg = col0 + wc*64 + ni*16 + fr;
      const float bv = bias[colg];
      #pragma unroll
      for (int rg = 0; rg < 4; ++rg) {
        const int rowg = row0 + wr*64 + mi*16 + hi*4 + rg;  // chunk-local
        outB[(size_t)rowg * N + colg] = (bf16_t)(acc0[mi][ni][rg] + bv);
      }
    }
  }
  if (doL) {
    #pragma unroll
    for (int mi = 0; mi < 4; ++mi) {
      #pragma unroll
      for (int ni = 0; ni < 4; ++ni) {
        const int colg = col0 + wc*64 + ni*16 + fr;
        #pragma unroll
        for (int rg = 0; rg < 4; ++rg) {
          const int rowg = row0 + wr*64 + mi*16 + hi*4 + rg;
          outL[(size_t)rowg * N + colg] = (bf16_t)(acc1[mi][ni][rg]);
        }
      }
    }
  }
}

// ---------------- combine1: x1 = gelu(base1 + sum_k normw*L1[k]), in-place; mask-skip reads ----------------
__global__ void combine1_kernel(bf16_t* __restrict__ base1, const bf16_t* __restrict__ L1,
                                const float* __restrict__ normw, const int* __restrict__ mask,
                                int P, int chunkOff) {
  int idx = blockIdx.x * blockDim.x + threadIdx.x;
  if (idx >= P * (HDIM/8)) return;
  int h0 = (idx % (HDIM/8)) * 8;
  int p  = idx / (HDIM/8);
  const int b = (chunkOff + p) >> 10;
  float lv[4][8];
  #pragma unroll
  for (int k = 0; k < 4; ++k) {
    if (mask[k*NB + b] != 0) {          // masked streams contribute exactly 0 — skip read
      bf16x8 v = *reinterpret_cast<const bf16x8*>(&L1[((size_t)(k*P + p))*HDIM + h0]);
      #pragma unroll
      for (int j = 0; j < 8; ++j) lv[k][j] = (float)v[j];
    } else {
      #pragma unroll
      for (int j = 0; j < 8; ++j) lv[k][j] = 0.f;
    }
  }
  #pragma unroll
  for (int i = 0; i < 4; ++i) {
    size_t ro = ((size_t)(i*P + p))*HDIM + h0;
    const float* nw = normw + ((size_t)(i*RPM + chunkOff + p))*4;
    float n0 = nw[0], n1 = nw[1], n2 = nw[2], n3 = nw[3];
    bf16x8 bv = *reinterpret_cast<const bf16x8*>(&base1[ro]);
    bf16x8 ov;
    #pragma unroll
    for (int j = 0; j < 8; ++j) {
      float v = (float)bv[j] + n0*lv[0][j] + n1*lv[1][j] + n2*lv[2][j] + n3*lv[3][j];
      float g = 0.5f * v * (1.f + erff(v * 0.70710678118654752f));  // exact gelu
      ov[j] = (bf16_t)g;
    }
    *reinterpret_cast<bf16x8*>(&base1[ro]) = ov;
  }
}

// ---------------- combine2: out = base2 + sum_k normw*L2[k]  (f32 out); mask-skip reads ----------------
__global__ void combine2_kernel(const bf16_t* __restrict__ base2, const bf16_t* __restrict__ L2,
                                const float* __restrict__ normw, const int* __restrict__ mask,
                                float* __restrict__ out, int P, int chunkOff) {
  int idx = blockIdx.x * blockDim.x + threadIdx.x;
  if (idx >= P * (CDIM/8)) return;
  int c0 = (idx % (CDIM/8)) * 8;
  int p  = idx / (CDIM/8);
  const int b = (chunkOff + p) >> 10;
  float lv[4][8];
  #pragma unroll
  for (int k = 0; k < 4; ++k) {
    if (mask[k*NB + b] != 0) {
      bf16x8 v = *reinterpret_cast<const bf16x8*>(&L2[((size_t)(k*P + p))*CDIM + c0]);
      #pragma unroll
      for (int j = 0; j < 8; ++j) lv[k][j] = (float)v[j];
    } else {
      #pragma unroll
      for (int j = 0; j < 8; ++j) lv[k][j] = 0.f;
    }
  }
  #pragma unroll
  for (int i = 0; i < 4; ++i) {
    int grow = i*RPM + chunkOff + p;
    const float* nw = normw + (size_t)grow*4;
    float n0 = nw[0], n1 = nw[1], n2 = nw[2], n3 = nw[3];
    bf16x8 bv = *reinterpret_cast<const bf16x8*>(&base2[((size_t)(i*P + p))*CDIM + c0]);
    float o[8];
    #pragma unroll
    for (int j = 0; j < 8; ++j)
      o[j] = (float)bv[j] + n0*lv[0][j] + n1*lv[1][j] + n2*lv[2][j] + n3*lv[3][j];
    float4* op = reinterpret_cast<float4*>(out + (size_t)grow*CDIM + c0);
    op[0] = make_float4(o[0], o[1], o[2], o[3]);
    op[1] = make_float4(o[4], o[5], o[6], o[7]);
  }
}

extern "C" void kernel_launch(void* const* d_in, const int* in_sizes, int n_in,
                              void* d_out, int out_size, void* d_ws, size_t ws_size,
                              hipStream_t stream) {
  (void)in_sizes; (void)n_in; (void)out_size;
  const float* x    = (const float*)d_in[0];
  const float* fc1w = (const float*)d_in[1];
  const float* fc1b = (const float*)d_in[2];
  const float* fc2w = (const float*)d_in[3];
  const float* fc2b = (const float*)d_in[4];
  const float* a1   = (const float*)d_in[5];
  const float* b1   = (const float*)d_in[6];
  const float* a2   = (const float*)d_in[7];
  const float* b2   = (const float*)d_in[8];
  const float* gw   = (const float*)d_in[9];
  const float* gb   = (const float*)d_in[10];
  const int*   mask = (const int*)d_in[11];
  float* out = (float*)d_out;

  char* ws = (char*)d_ws;
  size_t off = 0;
  auto carve = [&](size_t bytes) -> char* {
    char* p = ws + off; off += (bytes + 255) & ~(size_t)255; return p;
  };
  // fixed buffers: 72.7 MB
  bf16_t* x_bf  = (bf16_t*)carve((size_t)MROWS*CDIM*2);
  bf16_t* w1_bf = (bf16_t*)carve((size_t)HDIM*CDIM*2);
  bf16_t* w2_bf = (bf16_t*)carve((size_t)CDIM*HDIM*2);
  bf16_t* d1_bf = (bf16_t*)carve((size_t)NMOD*HDIM*CDIM*2);
  bf16_t* d2_bf = (bf16_t*)carve((size_t)NMOD*CDIM*HDIM*2);
  float*  normw = (float*)carve((size_t)MROWS*4*4);
  const size_t fixedBytes = off;

  // per-chunk: base1 (4P*H*2) + Lbuf (4P*H*2; stage2's base2+L2 reuse Lbuf after combine1)
  int P = RPM;  // 4096
  while (P > 128 && fixedBytes + (size_t)49152*P + 4096 > ws_size) P >>= 1;
  const int NCH = RPM / P;

  bf16_t* base1 = (bf16_t*)carve((size_t)NMOD*P*HDIM*2);  // becomes x1 in-place
  bf16_t* Lbuf  = (bf16_t*)carve((size_t)NMOD*P*HDIM*2);  // L1; then base2+L2
  bf16_t* L1    = Lbuf;
  bf16_t* base2 = Lbuf;                                   // 4P*CDIM*2
  bf16_t* L2    = Lbuf + (size_t)NMOD*P*CDIM;             // 4P*CDIM*2 (fits: 2*C <= H)

  // precompute (independent; weight converts fused into delta kernels)
  delta1_kernel<<<NMOD*HDIM*CDIM/256, 256, 0, stream>>>(fc1w, a1, b1, d1_bf, w1_bf);
  delta2_kernel<<<NMOD*CDIM*HDIM/256, 256, 0, stream>>>(fc2w, a2, b2, d2_bf, w2_bf);
  gate_kernel<<<MROWS/4, 256, 0, stream>>>(x, gw, gb, mask, normw, x_bf);

  for (int g = 0; g < NCH; ++g) {
    const int chunkOff = g * P;
    // stage 1: merged base+lora fc1 over 4P rows (K=768)
    gemm_kernel<<<dim3(NMOD*P/BMT, HDIM/BNT), 256, 0, stream>>>(
        x_bf, w1_bf, d1_bf, fc1b, mask, base1, L1, CDIM, HDIM, P, RPM, chunkOff, chunkOff);
    combine1_kernel<<<(P*(HDIM/8) + 255)/256, 256, 0, stream>>>(base1, L1, normw, mask, P, chunkOff);
    // stage 2: merged base+lora fc2 (A = x1 in base1; K=3072; outputs overlay dead L1)
    gemm_kernel<<<dim3(NMOD*P/BMT, CDIM/BNT), 256, 0, stream>>>(
        base1, w2_bf, d2_bf, fc2b, mask, base2, L2, HDIM, CDIM, P, P, 0, chunkOff);
    combine2_kernel<<<(P*(CDIM/8) + 255)/256, 256, 0, stream>>>(base2, L2, normw, mask, out, P, chunkOff);
  }
}

// Round 12
// 452.849 us; speedup vs baseline: 1.0125x; 1.0125x over previous
//
#include <hip/hip_runtime.h>
#include <hip/hip_bf16.h>
#include <math.h>

#define NMOD 4
#define NB 4
#define NTOKN 1024
#define CDIM 768
#define HDIM 3072
#define RDIM 16
#define MROWS (NMOD*NB*NTOKN)   // 16384 token rows
#define RPM (NB*NTOKN)          // 4096 positions per modality

typedef __bf16 bf16_t;
typedef __bf16 bf16x8 __attribute__((ext_vector_type(8)));
typedef float f32x4 __attribute__((ext_vector_type(4)));

// ---------------- delta1[k][h][c] = fc1_w[h][c] * (B@A); k==0 also emits fc1_w in bf16 ----------------
__global__ void delta1_kernel(const float* __restrict__ fc1w, const float* __restrict__ a1,
                              const float* __restrict__ b1, bf16_t* __restrict__ out,
                              bf16_t* __restrict__ w_bf) {
  int idx = blockIdx.x * blockDim.x + threadIdx.x;
  if (idx >= NMOD*HDIM*CDIM) return;
  int c = idx % CDIM;
  int h = (idx / CDIM) % HDIM;
  int k = idx / (CDIM*HDIM);
  const float* brow = b1 + ((size_t)k*HDIM + h)*RDIM;
  const float* acol = a1 + (size_t)k*RDIM*CDIM + c;
  float s = 0.f;
  #pragma unroll
  for (int r = 0; r < RDIM; ++r) s += brow[r] * acol[r*CDIM];
  const float wv = fc1w[h*CDIM + c];
  out[idx] = (bf16_t)(wv * s);
  if (k == 0) w_bf[h*CDIM + c] = (bf16_t)wv;   // fused weight convert
}

__global__ void delta2_kernel(const float* __restrict__ fc2w, const float* __restrict__ a2,
                              const float* __restrict__ b2, bf16_t* __restrict__ out,
                              bf16_t* __restrict__ w_bf) {
  int idx = blockIdx.x * blockDim.x + threadIdx.x;
  if (idx >= NMOD*CDIM*HDIM) return;
  int h = idx % HDIM;
  int c = (idx / HDIM) % CDIM;
  int k = idx / (HDIM*CDIM);
  const float* brow = b2 + ((size_t)k*CDIM + c)*RDIM;
  const float* acol = a2 + (size_t)k*RDIM*HDIM + h;
  float s = 0.f;
  #pragma unroll
  for (int r = 0; r < RDIM; ++r) s += brow[r] * acol[r*HDIM];
  const float wv = fc2w[c*HDIM + h];
  out[idx] = (bf16_t)(wv * s);
  if (k == 0) w_bf[c*HDIM + h] = (bf16_t)wv;   // fused weight convert
}

// ---------------- gating: normw[t][k]; fused x->bf16; 4 tokens/block ----------------
__global__ void gate_kernel(const float* __restrict__ x, const float* __restrict__ gw,
                            const float* __restrict__ gb, const int* __restrict__ mask,
                            float* __restrict__ normw, bf16_t* __restrict__ x_bf) {
  int t = blockIdx.x * 4 + (threadIdx.x >> 6);
  int lane = threadIdx.x & 63;
  int i = t >> 12;
  int b = (t >> 10) & 3;
  const float* xr = x + (size_t)t * CDIM;
  bf16_t* xo = x_bf + (size_t)t * CDIM;
  float acc[NMOD] = {0.f, 0.f, 0.f, 0.f};
  for (int c = lane; c < CDIM; c += 64) {
    float xv = xr[c];
    xo[c] = (bf16_t)xv;
    #pragma unroll
    for (int e = 0; e < NMOD; ++e) acc[e] += xv * gw[(i*NMOD + e)*CDIM + c];
  }
  #pragma unroll
  for (int e = 0; e < NMOD; ++e) {
    float v = acc[e];
    #pragma unroll
    for (int off = 32; off > 0; off >>= 1) v += __shfl_xor(v, off);
    acc[e] = v;
  }
  if (lane == 0) {
    float lg[NMOD], mx = -1e30f;
    #pragma unroll
    for (int e = 0; e < NMOD; ++e) { lg[e] = acc[e] + gb[i*NMOD + e]; mx = fmaxf(mx, lg[e]); }
    float s = 0.f;
    #pragma unroll
    for (int e = 0; e < NMOD; ++e) { lg[e] = expf(lg[e] - mx); s += lg[e]; }
    float inv = 1.f / s;
    float num[NMOD], den = 0.f;
    #pragma unroll
    for (int k = 0; k < NMOD; ++k) {
      float mk = (float)mask[k*NB + b];
      num[k] = lg[k] * inv * mk;
      den += num[k];
    }
    float mi = (float)mask[i*NB + b];
    float scale = mi / (den + 1e-6f);
    #pragma unroll
    for (int k = 0; k < NMOD; ++k) normw[(size_t)t*4 + k] = num[k] * scale;
  }
}

// ---------------- bf16 MFMA GEMM: swizzled + register-prefetch overlap ----------------
// out[row][col] = A[row,:] . W[col,:]  (W stored [N,K]); chunk of 4P rows.
// grid: (4P/128, N/128, 2); z=0: base W0 (+bias) -> outB; z=1: WL[mod] -> outL (mask-skip).
// Per K-step: (1) ds_read ALL frags of tile t -> regs, (2) __syncthreads [LDS free],
// (3) STAGE tile t+1 into the SAME buffer, (4) sched_barrier(0) pins loads before MFMA,
// (5) 32 MFMA from regs — loads fly UNDER compute, (6) __syncthreads (vmcnt0 drain lands
// after compute already covered most latency). Single 32KiB buffer, full-fence: race-free.
#define BMT 128
#define BNT 128
#define BKT 64

__device__ __forceinline__ void gload_lds16(const bf16_t* g, bf16_t* l) {
  __builtin_amdgcn_global_load_lds((const __attribute__((address_space(1))) void*)g,
                                   (__attribute__((address_space(3))) void*)l, 16, 0, 0);
}
#define MFMA_BF16 __builtin_amdgcn_mfma_f32_16x16x32_bf16

__global__ __launch_bounds__(256, 3)
void gemm_kernel(const bf16_t* __restrict__ A, const bf16_t* __restrict__ W0,
                 const bf16_t* __restrict__ WL, const float* __restrict__ bias,
                 const int* __restrict__ mask,
                 bf16_t* __restrict__ outB, bf16_t* __restrict__ outL,
                 int K, int N, int P, int modStride, int rowOff, int posOff) {
  __shared__ __align__(16) bf16_t As[BMT * BKT];
  __shared__ __align__(16) bf16_t Bs[BNT * BKT];

  const int tid  = threadIdx.x;
  const int lane = tid & 63;
  const int wv   = tid >> 6;
  const int wr   = wv >> 1, wc = wv & 1;
  const int row0 = blockIdx.x * BMT;   // chunk-local
  const int col0 = blockIdx.y * BNT;
  const bool lora = (blockIdx.z != 0);

  const int mod = row0 / P;            // P % 128 == 0
  if (lora) {
    const int bb = (posOff + (row0 % P)) >> 10;
    if (mask[mod*NB + bb] == 0) return;    // outputs get weight 0.0 in combine
  }
  const int gArow0 = mod * modStride + rowOff + (row0 % P);
  const bf16_t* Wp = lora ? (WL + (size_t)mod * N * K) : W0;

  // staging: 4 rounds of 32 rows; source col-slot swizzled, LDS dest linear (tid*16B)
  const int ldr = tid >> 3;                    // 0..31 (row; row&7 == ldr&7)
  const int ssl = ((tid & 7) ^ (ldr & 7)) * 8; // swizzled source col (elems)
  const bf16_t* Ag = A  + (size_t)(gArow0 + ldr) * K + ssl;
  const bf16_t* Wg = Wp + (size_t)(col0   + ldr) * K + ssl;

#define STAGE(k0_) do {                                                      \
    _Pragma("unroll")                                                        \
    for (int j_ = 0; j_ < 4; ++j_)                                           \
      gload_lds16(Ag + (size_t)(j_*32)*K + (k0_), &As[tid*8 + j_*2048]);     \
    _Pragma("unroll")                                                        \
    for (int j_ = 0; j_ < 4; ++j_)                                           \
      gload_lds16(Wg + (size_t)(j_*32)*K + (k0_), &Bs[tid*8 + j_*2048]);     \
  } while (0)

  // reads: source slot (kk*4+hi) at row r lives at LDS slot (kk*4+hi)^(r&7); r&7 == fr&7
  const int fr  = lane & 15;
  const int hi  = lane >> 4;
  const int sk0 = ((hi)     ^ (fr & 7)) * 8;   // kk=0
  const int sk1 = ((4 + hi) ^ (fr & 7)) * 8;   // kk=1

  f32x4 acc[4][4];
  #pragma unroll
  for (int i = 0; i < 4; ++i)
    #pragma unroll
    for (int j = 0; j < 4; ++j) acc[i][j] = (f32x4){0.f, 0.f, 0.f, 0.f};

  const int NT = K / BKT;

  STAGE(0);
  __syncthreads();                    // tile 0 ready

  for (int t = 0; t < NT; ++t) {
    // (1) read ALL fragments of tile t into registers
    bf16x8 af[2][4], bfr[2][4];
    #pragma unroll
    for (int mi = 0; mi < 4; ++mi) {
      af[0][mi] = *reinterpret_cast<const bf16x8*>(&As[(wr*64 + mi*16 + fr)*BKT + sk0]);
      af[1][mi] = *reinterpret_cast<const bf16x8*>(&As[(wr*64 + mi*16 + fr)*BKT + sk1]);
    }
    #pragma unroll
    for (int ni = 0; ni < 4; ++ni) {
      bfr[0][ni] = *reinterpret_cast<const bf16x8*>(&Bs[(wc*64 + ni*16 + fr)*BKT + sk0]);
      bfr[1][ni] = *reinterpret_cast<const bf16x8*>(&Bs[(wc*64 + ni*16 + fr)*BKT + sk1]);
    }
    __syncthreads();                  // (2) all waves done reading LDS (lgkm drained)

    if (t + 1 < NT) STAGE((t + 1) * BKT);   // (3) refill same buffer — flies under MFMA
    __builtin_amdgcn_sched_barrier(0);      // (4) pin: loads issue before MFMA cluster

    #pragma unroll
    for (int kk = 0; kk < 2; ++kk)
      #pragma unroll
      for (int mi = 0; mi < 4; ++mi)
        #pragma unroll
        for (int ni = 0; ni < 4; ++ni)
          acc[mi][ni] = MFMA_BF16(af[kk][mi], bfr[kk][ni], acc[mi][ni], 0, 0, 0);

    __syncthreads();                  // (6) drains stage loads: tile t+1 published
  }
#undef STAGE

  bf16_t* outp = lora ? outL : outB;
  #pragma unroll
  for (int mi = 0; mi < 4; ++mi) {
    #pragma unroll
    for (int ni = 0; ni < 4; ++ni) {
      const int colg = col0 + wc*64 + ni*16 + fr;
      float bv = 0.f;
      if (!lora) bv = bias[colg];
      #pragma unroll
      for (int rg = 0; rg < 4; ++rg) {
        const int rowg = row0 + wr*64 + mi*16 + hi*4 + rg;  // chunk-local
        outp[(size_t)rowg * N + colg] = (bf16_t)(acc[mi][ni][rg] + bv);
      }
    }
  }
}

// ---------------- combine1: x1 = gelu(base1 + sum_k normw*L1[k]), in-place; mask-skip reads ----------------
__global__ void combine1_kernel(bf16_t* __restrict__ base1, const bf16_t* __restrict__ L1,
                                const float* __restrict__ normw, const int* __restrict__ mask,
                                int P, int chunkOff) {
  int idx = blockIdx.x * blockDim.x + threadIdx.x;
  if (idx >= P * (HDIM/8)) return;
  int h0 = (idx % (HDIM/8)) * 8;
  int p  = idx / (HDIM/8);
  const int b = (chunkOff + p) >> 10;
  float lv[4][8];
  #pragma unroll
  for (int k = 0; k < 4; ++k) {
    if (mask[k*NB + b] != 0) {          // masked streams contribute exactly 0 — skip read
      bf16x8 v = *reinterpret_cast<const bf16x8*>(&L1[((size_t)(k*P + p))*HDIM + h0]);
      #pragma unroll
      for (int j = 0; j < 8; ++j) lv[k][j] = (float)v[j];
    } else {
      #pragma unroll
      for (int j = 0; j < 8; ++j) lv[k][j] = 0.f;
    }
  }
  #pragma unroll
  for (int i = 0; i < 4; ++i) {
    size_t ro = ((size_t)(i*P + p))*HDIM + h0;
    const float* nw = normw + ((size_t)(i*RPM + chunkOff + p))*4;
    float n0 = nw[0], n1 = nw[1], n2 = nw[2], n3 = nw[3];
    bf16x8 bv = *reinterpret_cast<const bf16x8*>(&base1[ro]);
    bf16x8 ov;
    #pragma unroll
    for (int j = 0; j < 8; ++j) {
      float v = (float)bv[j] + n0*lv[0][j] + n1*lv[1][j] + n2*lv[2][j] + n3*lv[3][j];
      float g = 0.5f * v * (1.f + erff(v * 0.70710678118654752f));  // exact gelu
      ov[j] = (bf16_t)g;
    }
    *reinterpret_cast<bf16x8*>(&base1[ro]) = ov;
  }
}

// ---------------- combine2: out = base2 + sum_k normw*L2[k]  (f32 out); mask-skip reads ----------------
__global__ void combine2_kernel(const bf16_t* __restrict__ base2, const bf16_t* __restrict__ L2,
                                const float* __restrict__ normw, const int* __restrict__ mask,
                                float* __restrict__ out, int P, int chunkOff) {
  int idx = blockIdx.x * blockDim.x + threadIdx.x;
  if (idx >= P * (CDIM/8)) return;
  int c0 = (idx % (CDIM/8)) * 8;
  int p  = idx / (CDIM/8);
  const int b = (chunkOff + p) >> 10;
  float lv[4][8];
  #pragma unroll
  for (int k = 0; k < 4; ++k) {
    if (mask[k*NB + b] != 0) {
      bf16x8 v = *reinterpret_cast<const bf16x8*>(&L2[((size_t)(k*P + p))*CDIM + c0]);
      #pragma unroll
      for (int j = 0; j < 8; ++j) lv[k][j] = (float)v[j];
    } else {
      #pragma unroll
      for (int j = 0; j < 8; ++j) lv[k][j] = 0.f;
    }
  }
  #pragma unroll
  for (int i = 0; i < 4; ++i) {
    int grow = i*RPM + chunkOff + p;
    const float* nw = normw + (size_t)grow*4;
    float n0 = nw[0], n1 = nw[1], n2 = nw[2], n3 = nw[3];
    bf16x8 bv = *reinterpret_cast<const bf16x8*>(&base2[((size_t)(i*P + p))*CDIM + c0]);
    float o[8];
    #pragma unroll
    for (int j = 0; j < 8; ++j)
      o[j] = (float)bv[j] + n0*lv[0][j] + n1*lv[1][j] + n2*lv[2][j] + n3*lv[3][j];
    float4* op = reinterpret_cast<float4*>(out + (size_t)grow*CDIM + c0);
    op[0] = make_float4(o[0], o[1], o[2], o[3]);
    op[1] = make_float4(o[4], o[5], o[6], o[7]);
  }
}

extern "C" void kernel_launch(void* const* d_in, const int* in_sizes, int n_in,
                              void* d_out, int out_size, void* d_ws, size_t ws_size,
                              hipStream_t stream) {
  (void)in_sizes; (void)n_in; (void)out_size;
  const float* x    = (const float*)d_in[0];
  const float* fc1w = (const float*)d_in[1];
  const float* fc1b = (const float*)d_in[2];
  const float* fc2w = (const float*)d_in[3];
  const float* fc2b = (const float*)d_in[4];
  const float* a1   = (const float*)d_in[5];
  const float* b1   = (const float*)d_in[6];
  const float* a2   = (const float*)d_in[7];
  const float* b2   = (const float*)d_in[8];
  const float* gw   = (const float*)d_in[9];
  const float* gb   = (const float*)d_in[10];
  const int*   mask = (const int*)d_in[11];
  float* out = (float*)d_out;

  char* ws = (char*)d_ws;
  size_t off = 0;
  auto carve = [&](size_t bytes) -> char* {
    char* p = ws + off; off += (bytes + 255) & ~(size_t)255; return p;
  };
  // fixed buffers: 72.7 MB
  bf16_t* x_bf  = (bf16_t*)carve((size_t)MROWS*CDIM*2);
  bf16_t* w1_bf = (bf16_t*)carve((size_t)HDIM*CDIM*2);
  bf16_t* w2_bf = (bf16_t*)carve((size_t)CDIM*HDIM*2);
  bf16_t* d1_bf = (bf16_t*)carve((size_t)NMOD*HDIM*CDIM*2);
  bf16_t* d2_bf = (bf16_t*)carve((size_t)NMOD*CDIM*HDIM*2);
  float*  normw = (float*)carve((size_t)MROWS*4*4);
  const size_t fixedBytes = off;

  // per-chunk: base1 (4P*H*2) + Lbuf (4P*H*2; stage2's base2+L2 overlay Lbuf after combine1)
  int P = RPM;  // 4096
  while (P > 128 && fixedBytes + (size_t)49152*P + 4096 > ws_size) P >>= 1;
  const int NCH = RPM / P;

  bf16_t* base1 = (bf16_t*)carve((size_t)NMOD*P*HDIM*2);  // becomes x1 in-place
  bf16_t* Lbuf  = (bf16_t*)carve((size_t)NMOD*P*HDIM*2);  // L1; then base2+L2
  bf16_t* L1    = Lbuf;
  bf16_t* base2 = Lbuf;                                   // 4P*CDIM*2
  bf16_t* L2    = Lbuf + (size_t)NMOD*P*CDIM;             // 4P*CDIM*2 (fits: 2*C <= H)

  // precompute (independent; weight converts fused into delta kernels)
  delta1_kernel<<<NMOD*HDIM*CDIM/256, 256, 0, stream>>>(fc1w, a1, b1, d1_bf, w1_bf);
  delta2_kernel<<<NMOD*CDIM*HDIM/256, 256, 0, stream>>>(fc2w, a2, b2, d2_bf, w2_bf);
  gate_kernel<<<MROWS/4, 256, 0, stream>>>(x, gw, gb, mask, normw, x_bf);

  for (int g = 0; g < NCH; ++g) {
    const int chunkOff = g * P;
    // stage 1: base fc1 + lora1 over 4P rows (K=768)
    gemm_kernel<<<dim3(NMOD*P/BMT, HDIM/BNT, 2), 256, 0, stream>>>(
        x_bf, w1_bf, d1_bf, fc1b, mask, base1, L1, CDIM, HDIM, P, RPM, chunkOff, chunkOff);
    combine1_kernel<<<(P*(HDIM/8) + 255)/256, 256, 0, stream>>>(base1, L1, normw, mask, P, chunkOff);
    // stage 2: base fc2 + lora2 (A = x1 in base1; K=3072; outputs overlay dead L1)
    gemm_kernel<<<dim3(NMOD*P/BMT, CDIM/BNT, 2), 256, 0, stream>>>(
        base1, w2_bf, d2_bf, fc2b, mask, base2, L2, HDIM, CDIM, P, P, 0, chunkOff);
    combine2_kernel<<<(P*(CDIM/8) + 255)/256, 256, 0, stream>>>(base2, L2, normw, mask, out, P, chunkOff);
  }
}

// Round 13
// 445.722 us; speedup vs baseline: 1.0287x; 1.0160x over previous
//
#include <hip/hip_runtime.h>
#include <hip/hip_bf16.h>
#include <math.h>

#define NMOD 4
#define NB 4
#define NTOKN 1024
#define CDIM 768
#define HDIM 3072
#define RDIM 16
#define MROWS (NMOD*NB*NTOKN)   // 16384 token rows
#define RPM (NB*NTOKN)          // 4096 positions per modality

typedef __bf16 bf16_t;
typedef __bf16 bf16x8 __attribute__((ext_vector_type(8)));
typedef float f32x4 __attribute__((ext_vector_type(4)));

// ---------------- delta1[k][h][c] = fc1_w[h][c] * (B@A); k==0 also emits fc1_w in bf16 ----------------
__global__ void delta1_kernel(const float* __restrict__ fc1w, const float* __restrict__ a1,
                              const float* __restrict__ b1, bf16_t* __restrict__ out,
                              bf16_t* __restrict__ w_bf) {
  int idx = blockIdx.x * blockDim.x + threadIdx.x;
  if (idx >= NMOD*HDIM*CDIM) return;
  int c = idx % CDIM;
  int h = (idx / CDIM) % HDIM;
  int k = idx / (CDIM*HDIM);
  const float* brow = b1 + ((size_t)k*HDIM + h)*RDIM;
  const float* acol = a1 + (size_t)k*RDIM*CDIM + c;
  float s = 0.f;
  #pragma unroll
  for (int r = 0; r < RDIM; ++r) s += brow[r] * acol[r*CDIM];
  const float wv = fc1w[h*CDIM + c];
  out[idx] = (bf16_t)(wv * s);
  if (k == 0) w_bf[h*CDIM + c] = (bf16_t)wv;   // fused weight convert
}

__global__ void delta2_kernel(const float* __restrict__ fc2w, const float* __restrict__ a2,
                              const float* __restrict__ b2, bf16_t* __restrict__ out,
                              bf16_t* __restrict__ w_bf) {
  int idx = blockIdx.x * blockDim.x + threadIdx.x;
  if (idx >= NMOD*CDIM*HDIM) return;
  int h = idx % HDIM;
  int c = (idx / HDIM) % CDIM;
  int k = idx / (HDIM*CDIM);
  const float* brow = b2 + ((size_t)k*CDIM + c)*RDIM;
  const float* acol = a2 + (size_t)k*RDIM*HDIM + h;
  float s = 0.f;
  #pragma unroll
  for (int r = 0; r < RDIM; ++r) s += brow[r] * acol[r*HDIM];
  const float wv = fc2w[c*HDIM + h];
  out[idx] = (bf16_t)(wv * s);
  if (k == 0) w_bf[c*HDIM + h] = (bf16_t)wv;   // fused weight convert
}

// ---------------- gating: normw[t][k]; fused x->bf16; 4 tokens/block ----------------
__global__ void gate_kernel(const float* __restrict__ x, const float* __restrict__ gw,
                            const float* __restrict__ gb, const int* __restrict__ mask,
                            float* __restrict__ normw, bf16_t* __restrict__ x_bf) {
  int t = blockIdx.x * 4 + (threadIdx.x >> 6);
  int lane = threadIdx.x & 63;
  int i = t >> 12;
  int b = (t >> 10) & 3;
  const float* xr = x + (size_t)t * CDIM;
  bf16_t* xo = x_bf + (size_t)t * CDIM;
  float acc[NMOD] = {0.f, 0.f, 0.f, 0.f};
  for (int c = lane; c < CDIM; c += 64) {
    float xv = xr[c];
    xo[c] = (bf16_t)xv;
    #pragma unroll
    for (int e = 0; e < NMOD; ++e) acc[e] += xv * gw[(i*NMOD + e)*CDIM + c];
  }
  #pragma unroll
  for (int e = 0; e < NMOD; ++e) {
    float v = acc[e];
    #pragma unroll
    for (int off = 32; off > 0; off >>= 1) v += __shfl_xor(v, off);
    acc[e] = v;
  }
  if (lane == 0) {
    float lg[NMOD], mx = -1e30f;
    #pragma unroll
    for (int e = 0; e < NMOD; ++e) { lg[e] = acc[e] + gb[i*NMOD + e]; mx = fmaxf(mx, lg[e]); }
    float s = 0.f;
    #pragma unroll
    for (int e = 0; e < NMOD; ++e) { lg[e] = expf(lg[e] - mx); s += lg[e]; }
    float inv = 1.f / s;
    float num[NMOD], den = 0.f;
    #pragma unroll
    for (int k = 0; k < NMOD; ++k) {
      float mk = (float)mask[k*NB + b];
      num[k] = lg[k] * inv * mk;
      den += num[k];
    }
    float mi = (float)mask[i*NB + b];
    float scale = mi / (den + 1e-6f);
    #pragma unroll
    for (int k = 0; k < NMOD; ++k) normw[(size_t)t*4 + k] = num[k] * scale;
  }
}

// ---------------- bf16 MFMA GEMM (r10-exact: swizzled, 4 blocks/CU, simple loop) ----------------
// out[row][col] = A[row,:] . W[col,:]  (W stored [N,K]); chunk of 4P rows.
// grid: (4P/128, N/128, 2); z=0: base W0 (+bias) -> outB; z=1: WL[mod] -> outL (mask-skip).
// Best-measured family member (r10: 78.6us/dispatch): stage -> sync -> compute -> sync,
// XOR-swizzled source+reads (0 bank conflicts), launch_bounds(256,4) for cross-block overlap.
#define BMT 128
#define BNT 128
#define BKT 64

__device__ __forceinline__ void gload_lds16(const bf16_t* g, bf16_t* l) {
  __builtin_amdgcn_global_load_lds((const __attribute__((address_space(1))) void*)g,
                                   (__attribute__((address_space(3))) void*)l, 16, 0, 0);
}
#define MFMA_BF16 __builtin_amdgcn_mfma_f32_16x16x32_bf16

__global__ __launch_bounds__(256, 4)
void gemm_kernel(const bf16_t* __restrict__ A, const bf16_t* __restrict__ W0,
                 const bf16_t* __restrict__ WL, const float* __restrict__ bias,
                 const int* __restrict__ mask,
                 bf16_t* __restrict__ outB, bf16_t* __restrict__ outL,
                 int K, int N, int P, int modStride, int rowOff, int posOff) {
  __shared__ __align__(16) bf16_t As[BMT * BKT];
  __shared__ __align__(16) bf16_t Bs[BNT * BKT];

  const int tid  = threadIdx.x;
  const int lane = tid & 63;
  const int wv   = tid >> 6;
  const int wr   = wv >> 1, wc = wv & 1;
  const int row0 = blockIdx.x * BMT;   // chunk-local
  const int col0 = blockIdx.y * BNT;
  const bool lora = (blockIdx.z != 0);

  const int mod = row0 / P;            // P % 128 == 0
  if (lora) {
    const int bb = (posOff + (row0 % P)) >> 10;
    if (mask[mod*NB + bb] == 0) return;    // outputs get weight 0.0 in combine
  }
  const int gArow0 = mod * modStride + rowOff + (row0 % P);
  const bf16_t* Wp = lora ? (WL + (size_t)mod * N * K) : W0;

  // staging: 4 rounds of 32 rows; source col-slot swizzled, LDS dest linear (tid*16B)
  const int ldr = tid >> 3;                    // 0..31 (row; row&7 == ldr&7)
  const int ssl = ((tid & 7) ^ (ldr & 7)) * 8; // swizzled source col (elems)
  const bf16_t* Ag = A  + (size_t)(gArow0 + ldr) * K + ssl;
  const bf16_t* Wg = Wp + (size_t)(col0   + ldr) * K + ssl;

  // reads: source slot (kk*4+hi) at row r lives at LDS slot (kk*4+hi)^(r&7); r&7 == fr&7
  const int fr  = lane & 15;
  const int hi  = lane >> 4;
  const int sk0 = ((hi)     ^ (fr & 7)) * 8;   // kk=0
  const int sk1 = ((4 + hi) ^ (fr & 7)) * 8;   // kk=1

  f32x4 acc[4][4];
  #pragma unroll
  for (int i = 0; i < 4; ++i)
    #pragma unroll
    for (int j = 0; j < 4; ++j) acc[i][j] = (f32x4){0.f, 0.f, 0.f, 0.f};

  for (int k0 = 0; k0 < K; k0 += BKT) {
    __syncthreads();  // protect LDS from overwrite while others still read
    #pragma unroll
    for (int j = 0; j < 4; ++j)
      gload_lds16(Ag + (size_t)(j*32) * K + k0, &As[tid*8 + j*2048]);
    #pragma unroll
    for (int j = 0; j < 4; ++j)
      gload_lds16(Wg + (size_t)(j*32) * K + k0, &Bs[tid*8 + j*2048]);
    __syncthreads();  // drains vmcnt(0) before s_barrier

    #pragma unroll
    for (int kk = 0; kk < 2; ++kk) {
      const int sk = (kk == 0) ? sk0 : sk1;
      bf16x8 af[4], bfr[4];
      #pragma unroll
      for (int mi = 0; mi < 4; ++mi)
        af[mi] = *reinterpret_cast<const bf16x8*>(&As[(wr*64 + mi*16 + fr)*BKT + sk]);
      #pragma unroll
      for (int ni = 0; ni < 4; ++ni)
        bfr[ni] = *reinterpret_cast<const bf16x8*>(&Bs[(wc*64 + ni*16 + fr)*BKT + sk]);
      #pragma unroll
      for (int mi = 0; mi < 4; ++mi)
        #pragma unroll
        for (int ni = 0; ni < 4; ++ni)
          acc[mi][ni] = MFMA_BF16(af[mi], bfr[ni], acc[mi][ni], 0, 0, 0);
    }
  }

  bf16_t* outp = lora ? outL : outB;
  #pragma unroll
  for (int mi = 0; mi < 4; ++mi) {
    #pragma unroll
    for (int ni = 0; ni < 4; ++ni) {
      const int colg = col0 + wc*64 + ni*16 + fr;
      float bv = 0.f;
      if (!lora) bv = bias[colg];
      #pragma unroll
      for (int rg = 0; rg < 4; ++rg) {
        const int rowg = row0 + wr*64 + mi*16 + hi*4 + rg;  // chunk-local
        outp[(size_t)rowg * N + colg] = (bf16_t)(acc[mi][ni][rg] + bv);
      }
    }
  }
}

// ---------------- combine1: x1 = gelu(base1 + sum_k normw*L1[k]), in-place; mask-skip reads ----------------
__global__ void combine1_kernel(bf16_t* __restrict__ base1, const bf16_t* __restrict__ L1,
                                const float* __restrict__ normw, const int* __restrict__ mask,
                                int P, int chunkOff) {
  int idx = blockIdx.x * blockDim.x + threadIdx.x;
  if (idx >= P * (HDIM/8)) return;
  int h0 = (idx % (HDIM/8)) * 8;
  int p  = idx / (HDIM/8);
  const int b = (chunkOff + p) >> 10;
  float lv[4][8];
  #pragma unroll
  for (int k = 0; k < 4; ++k) {
    if (mask[k*NB + b] != 0) {          // masked streams contribute exactly 0 — skip read
      bf16x8 v = *reinterpret_cast<const bf16x8*>(&L1[((size_t)(k*P + p))*HDIM + h0]);
      #pragma unroll
      for (int j = 0; j < 8; ++j) lv[k][j] = (float)v[j];
    } else {
      #pragma unroll
      for (int j = 0; j < 8; ++j) lv[k][j] = 0.f;
    }
  }
  #pragma unroll
  for (int i = 0; i < 4; ++i) {
    size_t ro = ((size_t)(i*P + p))*HDIM + h0;
    const float* nw = normw + ((size_t)(i*RPM + chunkOff + p))*4;
    float n0 = nw[0], n1 = nw[1], n2 = nw[2], n3 = nw[3];
    bf16x8 bv = *reinterpret_cast<const bf16x8*>(&base1[ro]);
    bf16x8 ov;
    #pragma unroll
    for (int j = 0; j < 8; ++j) {
      float v = (float)bv[j] + n0*lv[0][j] + n1*lv[1][j] + n2*lv[2][j] + n3*lv[3][j];
      float g = 0.5f * v * (1.f + erff(v * 0.70710678118654752f));  // exact gelu
      ov[j] = (bf16_t)g;
    }
    *reinterpret_cast<bf16x8*>(&base1[ro]) = ov;
  }
}

// ---------------- combine2: out = base2 + sum_k normw*L2[k]  (f32 out); mask-skip reads ----------------
__global__ void combine2_kernel(const bf16_t* __restrict__ base2, const bf16_t* __restrict__ L2,
                                const float* __restrict__ normw, const int* __restrict__ mask,
                                float* __restrict__ out, int P, int chunkOff) {
  int idx = blockIdx.x * blockDim.x + threadIdx.x;
  if (idx >= P * (CDIM/8)) return;
  int c0 = (idx % (CDIM/8)) * 8;
  int p  = idx / (CDIM/8);
  const int b = (chunkOff + p) >> 10;
  float lv[4][8];
  #pragma unroll
  for (int k = 0; k < 4; ++k) {
    if (mask[k*NB + b] != 0) {
      bf16x8 v = *reinterpret_cast<const bf16x8*>(&L2[((size_t)(k*P + p))*CDIM + c0]);
      #pragma unroll
      for (int j = 0; j < 8; ++j) lv[k][j] = (float)v[j];
    } else {
      #pragma unroll
      for (int j = 0; j < 8; ++j) lv[k][j] = 0.f;
    }
  }
  #pragma unroll
  for (int i = 0; i < 4; ++i) {
    int grow = i*RPM + chunkOff + p;
    const float* nw = normw + (size_t)grow*4;
    float n0 = nw[0], n1 = nw[1], n2 = nw[2], n3 = nw[3];
    bf16x8 bv = *reinterpret_cast<const bf16x8*>(&base2[((size_t)(i*P + p))*CDIM + c0]);
    float o[8];
    #pragma unroll
    for (int j = 0; j < 8; ++j)
      o[j] = (float)bv[j] + n0*lv[0][j] + n1*lv[1][j] + n2*lv[2][j] + n3*lv[3][j];
    float4* op = reinterpret_cast<float4*>(out + (size_t)grow*CDIM + c0);
    op[0] = make_float4(o[0], o[1], o[2], o[3]);
    op[1] = make_float4(o[4], o[5], o[6], o[7]);
  }
}

extern "C" void kernel_launch(void* const* d_in, const int* in_sizes, int n_in,
                              void* d_out, int out_size, void* d_ws, size_t ws_size,
                              hipStream_t stream) {
  (void)in_sizes; (void)n_in; (void)out_size;
  const float* x    = (const float*)d_in[0];
  const float* fc1w = (const float*)d_in[1];
  const float* fc1b = (const float*)d_in[2];
  const float* fc2w = (const float*)d_in[3];
  const float* fc2b = (const float*)d_in[4];
  const float* a1   = (const float*)d_in[5];
  const float* b1   = (const float*)d_in[6];
  const float* a2   = (const float*)d_in[7];
  const float* b2   = (const float*)d_in[8];
  const float* gw   = (const float*)d_in[9];
  const float* gb   = (const float*)d_in[10];
  const int*   mask = (const int*)d_in[11];
  float* out = (float*)d_out;

  char* ws = (char*)d_ws;
  size_t off = 0;
  auto carve = [&](size_t bytes) -> char* {
    char* p = ws + off; off += (bytes + 255) & ~(size_t)255; return p;
  };
  // fixed buffers: 72.7 MB
  bf16_t* x_bf  = (bf16_t*)carve((size_t)MROWS*CDIM*2);
  bf16_t* w1_bf = (bf16_t*)carve((size_t)HDIM*CDIM*2);
  bf16_t* w2_bf = (bf16_t*)carve((size_t)CDIM*HDIM*2);
  bf16_t* d1_bf = (bf16_t*)carve((size_t)NMOD*HDIM*CDIM*2);
  bf16_t* d2_bf = (bf16_t*)carve((size_t)NMOD*CDIM*HDIM*2);
  float*  normw = (float*)carve((size_t)MROWS*4*4);
  const size_t fixedBytes = off;

  // per-chunk: base1 (4P*H*2) + Lbuf (4P*H*2; stage2's base2+L2 overlay Lbuf after combine1)
  int P = RPM;  // 4096
  while (P > 128 && fixedBytes + (size_t)49152*P + 4096 > ws_size) P >>= 1;
  const int NCH = RPM / P;

  bf16_t* base1 = (bf16_t*)carve((size_t)NMOD*P*HDIM*2);  // becomes x1 in-place
  bf16_t* Lbuf  = (bf16_t*)carve((size_t)NMOD*P*HDIM*2);  // L1; then base2+L2
  bf16_t* L1    = Lbuf;
  bf16_t* base2 = Lbuf;                                   // 4P*CDIM*2
  bf16_t* L2    = Lbuf + (size_t)NMOD*P*CDIM;             // 4P*CDIM*2 (fits: 2*C <= H)

  // precompute (independent; weight converts fused into delta kernels)
  delta1_kernel<<<NMOD*HDIM*CDIM/256, 256, 0, stream>>>(fc1w, a1, b1, d1_bf, w1_bf);
  delta2_kernel<<<NMOD*CDIM*HDIM/256, 256, 0, stream>>>(fc2w, a2, b2, d2_bf, w2_bf);
  gate_kernel<<<MROWS/4, 256, 0, stream>>>(x, gw, gb, mask, normw, x_bf);

  for (int g = 0; g < NCH; ++g) {
    const int chunkOff = g * P;
    // stage 1: base fc1 + lora1 over 4P rows (K=768)
    gemm_kernel<<<dim3(NMOD*P/BMT, HDIM/BNT, 2), 256, 0, stream>>>(
        x_bf, w1_bf, d1_bf, fc1b, mask, base1, L1, CDIM, HDIM, P, RPM, chunkOff, chunkOff);
    combine1_kernel<<<(P*(HDIM/8) + 255)/256, 256, 0, stream>>>(base1, L1, normw, mask, P, chunkOff);
    // stage 2: base fc2 + lora2 (A = x1 in base1; K=3072; outputs overlay dead L1)
    gemm_kernel<<<dim3(NMOD*P/BMT, CDIM/BNT, 2), 256, 0, stream>>>(
        base1, w2_bf, d2_bf, fc2b, mask, base2, L2, HDIM, CDIM, P, P, 0, chunkOff);
    combine2_kernel<<<(P*(CDIM/8) + 255)/256, 256, 0, stream>>>(base2, L2, normw, mask, out, P, chunkOff);
  }
}

// Round 15
// 418.339 us; speedup vs baseline: 1.0961x; 1.0655x over previous
//
#include <hip/hip_runtime.h>
#include <hip/hip_bf16.h>
#include <math.h>

#define NMOD 4
#define NB 4
#define NTOKN 1024
#define CDIM 768
#define HDIM 3072
#define RDIM 16
#define MROWS (NMOD*NB*NTOKN)   // 16384 token rows
#define RPM (NB*NTOKN)          // 4096 positions per modality

typedef __bf16 bf16_t;
typedef __bf16 bf16x4 __attribute__((ext_vector_type(4)));
typedef __bf16 bf16x8 __attribute__((ext_vector_type(8)));
typedef float f32x4 __attribute__((ext_vector_type(4)));

// ---------------- delta1[k][h][c] = fc1_w[h][c] * (B@A); float4 along c; k==0 emits w_bf ----------------
__global__ void delta1_kernel(const float* __restrict__ fc1w, const float* __restrict__ a1,
                              const float* __restrict__ b1, bf16_t* __restrict__ out,
                              bf16_t* __restrict__ w_bf) {
  int idx = blockIdx.x * blockDim.x + threadIdx.x;
  if (idx >= NMOD*HDIM*(CDIM/4)) return;
  int c4 = (idx % (CDIM/4)) * 4;
  int h  = (idx / (CDIM/4)) % HDIM;
  int k  = idx / ((CDIM/4)*HDIM);
  const float* brow  = b1 + ((size_t)k*HDIM + h)*RDIM;
  const float* abase = a1 + (size_t)k*RDIM*CDIM + c4;
  float4 s = make_float4(0.f, 0.f, 0.f, 0.f);
  #pragma unroll
  for (int r = 0; r < RDIM; ++r) {
    const float br = brow[r];
    const float4 av = *reinterpret_cast<const float4*>(abase + (size_t)r*CDIM);
    s.x += br*av.x; s.y += br*av.y; s.z += br*av.z; s.w += br*av.w;
  }
  const float4 wv = *reinterpret_cast<const float4*>(fc1w + (size_t)h*CDIM + c4);
  bf16x4 o;
  o[0] = (bf16_t)(wv.x*s.x); o[1] = (bf16_t)(wv.y*s.y);
  o[2] = (bf16_t)(wv.z*s.z); o[3] = (bf16_t)(wv.w*s.w);
  *reinterpret_cast<bf16x4*>(out + ((size_t)k*HDIM + h)*CDIM + c4) = o;
  if (k == 0) {
    bf16x4 w4;
    w4[0] = (bf16_t)wv.x; w4[1] = (bf16_t)wv.y; w4[2] = (bf16_t)wv.z; w4[3] = (bf16_t)wv.w;
    *reinterpret_cast<bf16x4*>(w_bf + (size_t)h*CDIM + c4) = w4;
  }
}

// ---------------- delta2[k][c][h] = fc2_w[c][h] * (B@A); float4 along h; k==0 emits w_bf ----------------
__global__ void delta2_kernel(const float* __restrict__ fc2w, const float* __restrict__ a2,
                              const float* __restrict__ b2, bf16_t* __restrict__ out,
                              bf16_t* __restrict__ w_bf) {
  int idx = blockIdx.x * blockDim.x + threadIdx.x;
  if (idx >= NMOD*CDIM*(HDIM/4)) return;
  int h4 = (idx % (HDIM/4)) * 4;
  int c  = (idx / (HDIM/4)) % CDIM;
  int k  = idx / ((HDIM/4)*CDIM);
  const float* brow  = b2 + ((size_t)k*CDIM + c)*RDIM;
  const float* abase = a2 + (size_t)k*RDIM*HDIM + h4;
  float4 s = make_float4(0.f, 0.f, 0.f, 0.f);
  #pragma unroll
  for (int r = 0; r < RDIM; ++r) {
    const float br = brow[r];
    const float4 av = *reinterpret_cast<const float4*>(abase + (size_t)r*HDIM);
    s.x += br*av.x; s.y += br*av.y; s.z += br*av.z; s.w += br*av.w;
  }
  const float4 wv = *reinterpret_cast<const float4*>(fc2w + (size_t)c*HDIM + h4);
  bf16x4 o;
  o[0] = (bf16_t)(wv.x*s.x); o[1] = (bf16_t)(wv.y*s.y);
  o[2] = (bf16_t)(wv.z*s.z); o[3] = (bf16_t)(wv.w*s.w);
  *reinterpret_cast<bf16x4*>(out + ((size_t)k*CDIM + c)*HDIM + h4) = o;
  if (k == 0) {
    bf16x4 w4;
    w4[0] = (bf16_t)wv.x; w4[1] = (bf16_t)wv.y; w4[2] = (bf16_t)wv.z; w4[3] = (bf16_t)wv.w;
    *reinterpret_cast<bf16x4*>(w_bf + (size_t)c*HDIM + h4) = w4;
  }
}

// ---------------- gating: normw[t][k]; fused x->bf16 (float4 path); 4 tokens/block ----------------
__global__ void gate_kernel(const float* __restrict__ x, const float* __restrict__ gw,
                            const float* __restrict__ gb, const int* __restrict__ mask,
                            float* __restrict__ normw, bf16_t* __restrict__ x_bf) {
  int t = blockIdx.x * 4 + (threadIdx.x >> 6);
  int lane = threadIdx.x & 63;
  int i = t >> 12;
  int b = (t >> 10) & 3;
  const float4* xr4 = reinterpret_cast<const float4*>(x + (size_t)t * CDIM);
  const float4* gw4 = reinterpret_cast<const float4*>(gw);
  bf16x4* xo4 = reinterpret_cast<bf16x4*>(x_bf + (size_t)t * CDIM);
  float acc[NMOD] = {0.f, 0.f, 0.f, 0.f};
  #pragma unroll
  for (int j = 0; j < 3; ++j) {                 // 768/4 = 192 = 64 lanes * 3
    const int q = lane + j*64;
    const float4 xv = xr4[q];
    bf16x4 o;
    o[0] = (bf16_t)xv.x; o[1] = (bf16_t)xv.y; o[2] = (bf16_t)xv.z; o[3] = (bf16_t)xv.w;
    xo4[q] = o;
    #pragma unroll
    for (int e = 0; e < NMOD; ++e) {
      const float4 gv = gw4[(size_t)(i*NMOD + e)*(CDIM/4) + q];
      acc[e] += xv.x*gv.x + xv.y*gv.y + xv.z*gv.z + xv.w*gv.w;
    }
  }
  #pragma unroll
  for (int e = 0; e < NMOD; ++e) {
    float v = acc[e];
    #pragma unroll
    for (int off = 32; off > 0; off >>= 1) v += __shfl_xor(v, off);
    acc[e] = v;
  }
  if (lane == 0) {
    float lg[NMOD], mx = -1e30f;
    #pragma unroll
    for (int e = 0; e < NMOD; ++e) { lg[e] = acc[e] + gb[i*NMOD + e]; mx = fmaxf(mx, lg[e]); }
    float s = 0.f;
    #pragma unroll
    for (int e = 0; e < NMOD; ++e) { lg[e] = expf(lg[e] - mx); s += lg[e]; }
    float inv = 1.f / s;
    float num[NMOD], den = 0.f;
    #pragma unroll
    for (int k = 0; k < NMOD; ++k) {
      float mk = (float)mask[k*NB + b];
      num[k] = lg[k] * inv * mk;
      den += num[k];
    }
    float mi = (float)mask[i*NB + b];
    float scale = mi / (den + 1e-6f);
    #pragma unroll
    for (int k = 0; k < NMOD; ++k) normw[(size_t)t*4 + k] = num[k] * scale;
  }
}

// ---------------- bf16 MFMA GEMM (r10-exact: swizzled, 4 blocks/CU, simple loop) ----------------
// Best-measured family member (78.6us/dispatch over 7 structural variants r5-r12).
#define BMT 128
#define BNT 128
#define BKT 64

__device__ __forceinline__ void gload_lds16(const bf16_t* g, bf16_t* l) {
  __builtin_amdgcn_global_load_lds((const __attribute__((address_space(1))) void*)g,
                                   (__attribute__((address_space(3))) void*)l, 16, 0, 0);
}
#define MFMA_BF16 __builtin_amdgcn_mfma_f32_16x16x32_bf16

__global__ __launch_bounds__(256, 4)
void gemm_kernel(const bf16_t* __restrict__ A, const bf16_t* __restrict__ W0,
                 const bf16_t* __restrict__ WL, const float* __restrict__ bias,
                 const int* __restrict__ mask,
                 bf16_t* __restrict__ outB, bf16_t* __restrict__ outL,
                 int K, int N, int P, int modStride, int rowOff, int posOff) {
  __shared__ __align__(16) bf16_t As[BMT * BKT];
  __shared__ __align__(16) bf16_t Bs[BNT * BKT];

  const int tid  = threadIdx.x;
  const int lane = tid & 63;
  const int wv   = tid >> 6;
  const int wr   = wv >> 1, wc = wv & 1;
  const int row0 = blockIdx.x * BMT;   // chunk-local
  const int col0 = blockIdx.y * BNT;
  const bool lora = (blockIdx.z != 0);

  const int mod = row0 / P;            // P % 128 == 0
  if (lora) {
    const int bb = (posOff + (row0 % P)) >> 10;
    if (mask[mod*NB + bb] == 0) return;    // outputs get weight 0.0 in combine
  }
  const int gArow0 = mod * modStride + rowOff + (row0 % P);
  const bf16_t* Wp = lora ? (WL + (size_t)mod * N * K) : W0;

  // staging: 4 rounds of 32 rows; source col-slot swizzled, LDS dest linear (tid*16B)
  const int ldr = tid >> 3;                    // 0..31 (row; row&7 == ldr&7)
  const int ssl = ((tid & 7) ^ (ldr & 7)) * 8; // swizzled source col (elems)
  const bf16_t* Ag = A  + (size_t)(gArow0 + ldr) * K + ssl;
  const bf16_t* Wg = Wp + (size_t)(col0   + ldr) * K + ssl;

  // reads: source slot (kk*4+hi) at row r lives at LDS slot (kk*4+hi)^(r&7); r&7 == fr&7
  const int fr  = lane & 15;
  const int hi  = lane >> 4;
  const int sk0 = ((hi)     ^ (fr & 7)) * 8;   // kk=0
  const int sk1 = ((4 + hi) ^ (fr & 7)) * 8;   // kk=1

  f32x4 acc[4][4];
  #pragma unroll
  for (int i = 0; i < 4; ++i)
    #pragma unroll
    for (int j = 0; j < 4; ++j) acc[i][j] = (f32x4){0.f, 0.f, 0.f, 0.f};

  for (int k0 = 0; k0 < K; k0 += BKT) {
    __syncthreads();  // protect LDS from overwrite while others still read
    #pragma unroll
    for (int j = 0; j < 4; ++j)
      gload_lds16(Ag + (size_t)(j*32) * K + k0, &As[tid*8 + j*2048]);
    #pragma unroll
    for (int j = 0; j < 4; ++j)
      gload_lds16(Wg + (size_t)(j*32) * K + k0, &Bs[tid*8 + j*2048]);
    __syncthreads();  // drains vmcnt(0) before s_barrier

    #pragma unroll
    for (int kk = 0; kk < 2; ++kk) {
      const int sk = (kk == 0) ? sk0 : sk1;
      bf16x8 af[4], bfr[4];
      #pragma unroll
      for (int mi = 0; mi < 4; ++mi)
        af[mi] = *reinterpret_cast<const bf16x8*>(&As[(wr*64 + mi*16 + fr)*BKT + sk]);
      #pragma unroll
      for (int ni = 0; ni < 4; ++ni)
        bfr[ni] = *reinterpret_cast<const bf16x8*>(&Bs[(wc*64 + ni*16 + fr)*BKT + sk]);
      #pragma unroll
      for (int mi = 0; mi < 4; ++mi)
        #pragma unroll
        for (int ni = 0; ni < 4; ++ni)
          acc[mi][ni] = MFMA_BF16(af[mi], bfr[ni], acc[mi][ni], 0, 0, 0);
    }
  }

  bf16_t* outp = lora ? outL : outB;
  #pragma unroll
  for (int mi = 0; mi < 4; ++mi) {
    #pragma unroll
    for (int ni = 0; ni < 4; ++ni) {
      const int colg = col0 + wc*64 + ni*16 + fr;
      float bv = 0.f;
      if (!lora) bv = bias[colg];
      #pragma unroll
      for (int rg = 0; rg < 4; ++rg) {
        const int rowg = row0 + wr*64 + mi*16 + hi*4 + rg;  // chunk-local
        outp[(size_t)rowg * N + colg] = (bf16_t)(acc[mi][ni][rg] + bv);
      }
    }
  }
}

// ---------------- combine1: x1 = gelu(base1 + sum_k normw*L1[k]); NT loads on L1 ----------------
__global__ void combine1_kernel(bf16_t* __restrict__ base1, const bf16_t* __restrict__ L1,
                                const float* __restrict__ normw, const int* __restrict__ mask,
                                int P, int chunkOff) {
  int idx = blockIdx.x * blockDim.x + threadIdx.x;
  if (idx >= P * (HDIM/8)) return;
  int h0 = (idx % (HDIM/8)) * 8;
  int p  = idx / (HDIM/8);
  const int b = (chunkOff + p) >> 10;
  float lv[4][8];
  #pragma unroll
  for (int k = 0; k < 4; ++k) {
    if (mask[k*NB + b] != 0) {          // masked streams contribute exactly 0 — skip read
      f32x4 raw = __builtin_nontemporal_load(
          reinterpret_cast<const f32x4*>(&L1[((size_t)(k*P + p))*HDIM + h0]));
      bf16x8 v = *reinterpret_cast<bf16x8*>(&raw);
      #pragma unroll
      for (int j = 0; j < 8; ++j) lv[k][j] = (float)v[j];
    } else {
      #pragma unroll
      for (int j = 0; j < 8; ++j) lv[k][j] = 0.f;
    }
  }
  #pragma unroll
  for (int i = 0; i < 4; ++i) {
    size_t ro = ((size_t)(i*P + p))*HDIM + h0;
    const float* nw = normw + ((size_t)(i*RPM + chunkOff + p))*4;
    float n0 = nw[0], n1 = nw[1], n2 = nw[2], n3 = nw[3];
    bf16x8 bv = *reinterpret_cast<const bf16x8*>(&base1[ro]);
    bf16x8 ov;
    #pragma unroll
    for (int j = 0; j < 8; ++j) {
      float v = (float)bv[j] + n0*lv[0][j] + n1*lv[1][j] + n2*lv[2][j] + n3*lv[3][j];
      float g = 0.5f * v * (1.f + erff(v * 0.70710678118654752f));  // exact gelu
      ov[j] = (bf16_t)g;
    }
    *reinterpret_cast<bf16x8*>(&base1[ro]) = ov;   // x1 re-read by stage-2: keep temporal
  }
}

// ---------------- combine2: out = base2 + sum_k normw*L2[k] (f32); NT loads + NT stores ----------------
__global__ void combine2_kernel(const bf16_t* __restrict__ base2, const bf16_t* __restrict__ L2,
                                const float* __restrict__ normw, const int* __restrict__ mask,
                                float* __restrict__ out, int P, int chunkOff) {
  int idx = blockIdx.x * blockDim.x + threadIdx.x;
  if (idx >= P * (CDIM/8)) return;
  int c0 = (idx % (CDIM/8)) * 8;
  int p  = idx / (CDIM/8);
  const int b = (chunkOff + p) >> 10;
  float lv[4][8];
  #pragma unroll
  for (int k = 0; k < 4; ++k) {
    if (mask[k*NB + b] != 0) {
      f32x4 raw = __builtin_nontemporal_load(
          reinterpret_cast<const f32x4*>(&L2[((size_t)(k*P + p))*CDIM + c0]));
      bf16x8 v = *reinterpret_cast<bf16x8*>(&raw);
      #pragma unroll
      for (int j = 0; j < 8; ++j) lv[k][j] = (float)v[j];
    } else {
      #pragma unroll
      for (int j = 0; j < 8; ++j) lv[k][j] = 0.f;
    }
  }
  #pragma unroll
  for (int i = 0; i < 4; ++i) {
    int grow = i*RPM + chunkOff + p;
    const float* nw = normw + (size_t)grow*4;
    float n0 = nw[0], n1 = nw[1], n2 = nw[2], n3 = nw[3];
    f32x4 raw = __builtin_nontemporal_load(
        reinterpret_cast<const f32x4*>(&base2[((size_t)(i*P + p))*CDIM + c0]));
    bf16x8 bv = *reinterpret_cast<bf16x8*>(&raw);
    float o[8];
    #pragma unroll
    for (int j = 0; j < 8; ++j)
      o[j] = (float)bv[j] + n0*lv[0][j] + n1*lv[1][j] + n2*lv[2][j] + n3*lv[3][j];
    f32x4* op = reinterpret_cast<f32x4*>(out + (size_t)grow*CDIM + c0);
    __builtin_nontemporal_store((f32x4){o[0], o[1], o[2], o[3]}, op);      // out never re-read
    __builtin_nontemporal_store((f32x4){o[4], o[5], o[6], o[7]}, op + 1);
  }
}

extern "C" void kernel_launch(void* const* d_in, const int* in_sizes, int n_in,
                              void* d_out, int out_size, void* d_ws, size_t ws_size,
                              hipStream_t stream) {
  (void)in_sizes; (void)n_in; (void)out_size;
  const float* x    = (const float*)d_in[0];
  const float* fc1w = (const float*)d_in[1];
  const float* fc1b = (const float*)d_in[2];
  const float* fc2w = (const float*)d_in[3];
  const float* fc2b = (const float*)d_in[4];
  const float* a1   = (const float*)d_in[5];
  const float* b1   = (const float*)d_in[6];
  const float* a2   = (const float*)d_in[7];
  const float* b2   = (const float*)d_in[8];
  const float* gw   = (const float*)d_in[9];
  const float* gb   = (const float*)d_in[10];
  const int*   mask = (const int*)d_in[11];
  float* out = (float*)d_out;

  char* ws = (char*)d_ws;
  size_t off = 0;
  auto carve = [&](size_t bytes) -> char* {
    char* p = ws + off; off += (bytes + 255) & ~(size_t)255; return p;
  };
  // fixed buffers: 72.7 MB
  bf16_t* x_bf  = (bf16_t*)carve((size_t)MROWS*CDIM*2);
  bf16_t* w1_bf = (bf16_t*)carve((size_t)HDIM*CDIM*2);
  bf16_t* w2_bf = (bf16_t*)carve((size_t)CDIM*HDIM*2);
  bf16_t* d1_bf = (bf16_t*)carve((size_t)NMOD*HDIM*CDIM*2);
  bf16_t* d2_bf = (bf16_t*)carve((size_t)NMOD*CDIM*HDIM*2);
  float*  normw = (float*)carve((size_t)MROWS*4*4);
  const size_t fixedBytes = off;

  // per-chunk: base1 (4P*H*2) + Lbuf (4P*H*2; stage2's base2+L2 overlay Lbuf after combine1)
  int P = RPM;  // 4096
  while (P > 128 && fixedBytes + (size_t)49152*P + 4096 > ws_size) P >>= 1;
  const int NCH = RPM / P;

  bf16_t* base1 = (bf16_t*)carve((size_t)NMOD*P*HDIM*2);  // becomes x1 in-place
  bf16_t* Lbuf  = (bf16_t*)carve((size_t)NMOD*P*HDIM*2);  // L1; then base2+L2
  bf16_t* L1    = Lbuf;
  bf16_t* base2 = Lbuf;                                   // 4P*CDIM*2
  bf16_t* L2    = Lbuf + (size_t)NMOD*P*CDIM;             // 4P*CDIM*2 (fits: 2*C <= H)

  // precompute (independent; weight converts fused into delta kernels; all vectorized)
  delta1_kernel<<<NMOD*HDIM*(CDIM/4)/256, 256, 0, stream>>>(fc1w, a1, b1, d1_bf, w1_bf);
  delta2_kernel<<<NMOD*CDIM*(HDIM/4)/256, 256, 0, stream>>>(fc2w, a2, b2, d2_bf, w2_bf);
  gate_kernel<<<MROWS/4, 256, 0, stream>>>(x, gw, gb, mask, normw, x_bf);

  for (int g = 0; g < NCH; ++g) {
    const int chunkOff = g * P;
    // stage 1: base fc1 + lora1 over 4P rows (K=768)
    gemm_kernel<<<dim3(NMOD*P/BMT, HDIM/BNT, 2), 256, 0, stream>>>(
        x_bf, w1_bf, d1_bf, fc1b, mask, base1, L1, CDIM, HDIM, P, RPM, chunkOff, chunkOff);
    combine1_kernel<<<(P*(HDIM/8) + 255)/256, 256, 0, stream>>>(base1, L1, normw, mask, P, chunkOff);
    // stage 2: base fc2 + lora2 (A = x1 in base1; K=3072; outputs overlay dead L1)
    gemm_kernel<<<dim3(NMOD*P/BMT, CDIM/BNT, 2), 256, 0, stream>>>(
        base1, w2_bf, d2_bf, fc2b, mask, base2, L2, HDIM, CDIM, P, P, 0, chunkOff);
    combine2_kernel<<<(P*(CDIM/8) + 255)/256, 256, 0, stream>>>(base2, L2, normw, mask, out, P, chunkOff);
  }
}